// Round 8
// baseline (250.819 us; speedup 1.0000x reference)
//
#include <hip/hip_runtime.h>
#include <hip/hip_bf16.h>

typedef __bf16 bf16;
typedef __bf16 bf16x8 __attribute__((ext_vector_type(8)));
typedef __bf16 bf16x4 __attribute__((ext_vector_type(4)));
typedef __bf16 bf16x2 __attribute__((ext_vector_type(2)));
typedef float floatx4 __attribute__((ext_vector_type(4)));
typedef float floatx16 __attribute__((ext_vector_type(16)));

#define B_SZ 2
#define S_LEN 2048
#define D_DIM 1024
#define H_CNT 16
#define HD_DIM 64
#define M_ROWS 4096   // B*S
#define QSCALE 0.18033688011112042f  // 0.125 * log2(e): scores come out in base-2 domain

__device__ __forceinline__ void async_ld16(const bf16* g, bf16* s) {
    __builtin_amdgcn_global_load_lds((const __attribute__((address_space(1))) void*)g,
                                     (__attribute__((address_space(3))) void*)s, 16, 0, 0);
}

__device__ __forceinline__ floatx4 mfma16(bf16x8 a, bf16x8 b, floatx4 c) {
    return __builtin_amdgcn_mfma_f32_16x16x32_bf16(a, b, c, 0, 0, 0);
}
__device__ __forceinline__ floatx16 mfma32(bf16x8 a, bf16x8 b, floatx16 c) {
    return __builtin_amdgcn_mfma_f32_32x32x16_bf16(a, b, c, 0, 0, 0);
}

// ---------------- merged prep: input casts + all weight transposes, one launch ----------------
struct PrepArgs {
    const float* cast_src[3]; bf16* cast_dst[3];
    const float* w_src[3];    bf16* w_dst[3];
    const float* wo;          bf16* wo_t;
};
__global__ __launch_bounds__(256) void prep(PrepArgs a) {
    __shared__ bf16 tile[32][33];
    const int bx = blockIdx.x, tid = threadIdx.x;
    if (bx < 12288) {
        const int t = bx >> 12, blk = bx & 4095;
        const float* s = a.cast_src[t];
        bf16* d = a.cast_dst[t];
        size_t i = ((size_t)blk * 256 + tid) * 4;
        float4 v = *(const float4*)(s + i);
        bf16x4 o = { (bf16)v.x, (bf16)v.y, (bf16)v.z, (bf16)v.w };
        *(bf16x4*)(d + i) = o;
        return;
    }
    int tx = tid & 31, ty = tid >> 5;
    const float* src; bf16* dst; int r0, c0, C, R;
    if (bx < 15360) {
        int idx = bx - 12288;
        int z = idx >> 6, xy = idx & 63;
        int mat = z >> 4, head = z & 15;
        src = a.w_src[mat] + (size_t)head * D_DIM * HD_DIM;  // [1024][64]
        dst = a.w_dst[mat] + (size_t)head * D_DIM * HD_DIM;  // [64][1024]
        r0 = (xy & 31) * 32; c0 = (xy >> 5) * 32; C = HD_DIM; R = D_DIM;
    } else {
        int idx = bx - 15360;
        src = a.wo; dst = a.wo_t;
        r0 = (idx & 31) * 32; c0 = (idx >> 5) * 32; C = D_DIM; R = D_DIM;
    }
#pragma unroll
    for (int i = 0; i < 32; i += 8)
        tile[ty + i][tx] = (bf16)src[(size_t)(r0 + ty + i) * C + c0 + tx];
    __syncthreads();
#pragma unroll
    for (int i = 0; i < 32; i += 8)
        dst[(size_t)(c0 + ty + i) * R + r0 + tx] = tile[tx][ty + i];
}

// ---------------- batched bf16 transpose: dst[z][c][r] = src[z][r][c] ----------------
__global__ __launch_bounds__(256) void transpose2d(const bf16* __restrict__ src,
                                                   bf16* __restrict__ dst, int R, int C) {
    __shared__ bf16 tile[32][33];
    size_t zoff = (size_t)blockIdx.z * R * C;
    src += zoff; dst += zoff;
    int r0 = blockIdx.x * 32, c0 = blockIdx.y * 32;
    int tx = threadIdx.x & 31, ty = threadIdx.x >> 5;
#pragma unroll
    for (int i = 0; i < 32; i += 8) tile[ty + i][tx] = src[(size_t)(r0 + ty + i) * C + c0 + tx];
    __syncthreads();
#pragma unroll
    for (int i = 0; i < 32; i += 8) dst[(size_t)(c0 + ty + i) * R + r0 + tx] = tile[tx][ty + i];
}

// ------- GEMM: C = (A[4096x1024] * BT^T + bias) * scale, double-buffered K-loop -------
// Prefetch tile k+1 (async global->LDS) BEFORE computing tile k; single barrier/iter.
// The barrier's vmcnt(0) drain is covered by the 16 MFMAs issued in between.
struct GemmPtrs { const bf16* A; const bf16* BT; const float* bias; bf16* C; float* Cf; float scale; };
struct GemmArgs { GemmPtrs p[3]; int mode; };

__global__ __launch_bounds__(256) void gemm_bt(GemmArgs args) {
    __shared__ __align__(16) bf16 As[2][4096];
    __shared__ __align__(16) bf16 Bs[2][4096];
    const GemmPtrs P = args.p[blockIdx.z];
    const int tid = threadIdx.x, wave = tid >> 6, lane = tid & 63;
    const int quad = lane >> 4, l15 = lane & 15;
    const int bm = blockIdx.x * 128, bn = blockIdx.y * 128;
    const int wm = (wave >> 1) * 64, wn = (wave & 1) * 64;

    floatx4 acc[4][4];
#pragma unroll
    for (int i = 0; i < 4; i++)
#pragma unroll
        for (int j = 0; j < 4; j++) acc[i][j] = (floatx4){0.f, 0.f, 0.f, 0.f};

    const int srow = (lane >> 2);
    const int scol = (((lane & 3) ^ ((srow >> 1) & 3)) << 3);  // swizzled source chunk
    const int ck = ((quad ^ ((l15 >> 1) & 3)) << 3);           // swizzled read chunk

    // stage K-tile 0 into buffer 0
#pragma unroll
    for (int it = 0; it < 2; ++it) {
        int issue = it * 4 + wave;
        int row = issue * 16 + srow;
        async_ld16(P.A + (size_t)(bm + row) * 1024 + scol, &As[0][issue * 512]);
        async_ld16(P.BT + (size_t)(bn + row) * 1024 + scol, &Bs[0][issue * 512]);
    }
    __syncthreads();

    for (int i = 0; i < 32; ++i) {
        const int cur = i & 1;
        if (i < 31) {  // prefetch next K-tile into the other buffer
            int k0 = (i + 1) * 32;
#pragma unroll
            for (int it = 0; it < 2; ++it) {
                int issue = it * 4 + wave;
                int row = issue * 16 + srow;
                async_ld16(P.A + (size_t)(bm + row) * 1024 + k0 + scol, &As[cur ^ 1][issue * 512]);
                async_ld16(P.BT + (size_t)(bn + row) * 1024 + k0 + scol, &Bs[cur ^ 1][issue * 512]);
            }
        }
        bf16x8 af[4], bfr[4];
#pragma unroll
        for (int mi = 0; mi < 4; mi++)
            af[mi] = *(const bf16x8*)&As[cur][(wm + mi * 16 + l15) * 32 + ck];
#pragma unroll
        for (int ni = 0; ni < 4; ni++)
            bfr[ni] = *(const bf16x8*)&Bs[cur][(wn + ni * 16 + l15) * 32 + ck];
#pragma unroll
        for (int mi = 0; mi < 4; mi++)
#pragma unroll
            for (int ni = 0; ni < 4; ni++) acc[mi][ni] = mfma16(af[mi], bfr[ni], acc[mi][ni]);
        __syncthreads();
    }
#pragma unroll
    for (int ni = 0; ni < 4; ni++) {
        int col = bn + wn + ni * 16 + l15;
        float bb = P.bias[col];
#pragma unroll
        for (int mi = 0; mi < 4; mi++) {
#pragma unroll
            for (int r = 0; r < 4; r++) {
                int row = bm + wm + mi * 16 + quad * 4 + r;
                float v = (acc[mi][ni][r] + bb) * P.scale;
                if (args.mode == 0) {
                    P.Cf[(size_t)row * 1024 + col] = v;
                } else {
                    int b = row >> 11, s2 = row & 2047, h = col >> 6, hd = col & 63;
                    P.C[(((size_t)(b * H_CNT + h)) * S_LEN + s2) * HD_DIM + hd] = (bf16)v;
                }
            }
        }
    }
}

// ---------- flash attention, t-split 2-way, 32x32x16 MFMA, no-max softmax ----------
// Grid 1024 = 16 qb x 32 bh x 2 tp. Each block: 128 q rows x 1024 t (16 rounds of 64).
// No-max softmax => partials are exactly additive across t-parts: block writes
// unnormalized O_part (fp32, [tp][bh][s][hd]) + l_part; combine kernel merges.
// LDS 48 KB -> 3 blocks/CU (vs 2 at R7's 80 KB).
__global__ __launch_bounds__(256) void attn(const bf16* __restrict__ Qg, const bf16* __restrict__ Kg,
                                            const bf16* __restrict__ Vtg,
                                            float* __restrict__ Op, float* __restrict__ lp) {
    __shared__ __align__(16) bf16 SMEM[24576];   // Ks[2][4096] | Vs[2][4096] | Ps[4][2048]
    bf16* KsP = SMEM;
    bf16* VsP = SMEM + 8192;
    bf16* PsP = SMEM + 16384;
    const int tid = threadIdx.x, wave = tid >> 6, lane = tid & 63;
    const int l31 = lane & 31, half = lane >> 5;
    const int bid = blockIdx.x;
    const int bh = (bid >> 1) & 31;
    const int tp = bid & 1;
    const int qb = bid >> 6;
    const int q0blk = qb * 128;
    const int tbase0 = tp * 1024;
    const bf16* Kp = Kg + (size_t)bh * S_LEN * HD_DIM;
    const bf16* Vp = Vtg + (size_t)bh * HD_DIM * S_LEN;

    // stage K/V tile 0 of this t-part
#pragma unroll
    for (int it = 0; it < 2; ++it) {
        int i = it * 4 + wave;
        int f = i * 512 + lane * 8;
        int c = f >> 9, r = (f & 511) >> 3;
        async_ld16(Kp + (size_t)(tbase0 + r) * HD_DIM + c * 8, &KsP[i * 512]);
        async_ld16(Vp + (size_t)r * S_LEN + tbase0 + c * 8, &VsP[i * 512]);
    }
    // Q B-frags from global: B[q=wave*32+l31][k=(2kb+half)*8 + j]
    bf16x8 qf[4];
    {
        const bf16* qrow = Qg + ((size_t)bh * S_LEN + q0blk + wave * 32 + l31) * HD_DIM;
#pragma unroll
        for (int kb = 0; kb < 4; ++kb)
            qf[kb] = *(const bf16x8*)(qrow + (2 * kb + half) * 8);
    }
    __syncthreads();

    bf16* Pw = PsP + wave * 2048;
    float l_i = 0.f;
    floatx16 o0 = {0}, o1 = {0};   // O^T strips: rows hd 0-31 / 32-63, col q=l31

    for (int rd = 0; rd < 16; ++rd) {
        const int cur = rd & 1;
        if (rd < 15) {  // prefetch next 64-t tile
            int t0n = tbase0 + (rd + 1) * 64;
#pragma unroll
            for (int it = 0; it < 2; ++it) {
                int i = it * 4 + wave;
                int f = i * 512 + lane * 8;
                int c = f >> 9, r = (f & 511) >> 3;
                async_ld16(Kp + (size_t)(t0n + r) * HD_DIM + c * 8, &KsP[(cur ^ 1) * 4096 + i * 512]);
                async_ld16(Vp + (size_t)r * S_LEN + t0n + c * 8, &VsP[(cur ^ 1) * 4096 + i * 512]);
            }
        }
        const bf16* Kt = &KsP[cur * 4096];
        const bf16* Vt = &VsP[cur * 4096];
        // QK^T: sc[strip] rows t = 32*strip + (e&3)+8*(e>>2)+4*half, col q = l31
        floatx16 sc0 = {0}, sc1 = {0};
#pragma unroll
        for (int kb = 0; kb < 4; ++kb) {
            bf16x8 k0 = *(const bf16x8*)&Kt[(2 * kb + half) * 512 + l31 * 8];
            bf16x8 k1 = *(const bf16x8*)&Kt[(2 * kb + half) * 512 + (32 + l31) * 8];
            sc0 = mfma32(k0, qf[kb], sc0);
            sc1 = mfma32(k1, qf[kb], sc1);
        }
        // no-max softmax: P = exp2(score), native v_exp_f32
        float rs = 0.f;
#pragma unroll
        for (int e = 0; e < 16; e += 2) {   // strip 0: t = 0..31
            float p0 = __builtin_amdgcn_exp2f(sc0[e]);
            float p1 = __builtin_amdgcn_exp2f(sc0[e + 1]);
            rs += p0 + p1;
            *(bf16x2*)&Pw[(e >> 2) * 256 + l31 * 8 + (e & 3) + 4 * half] = (bf16x2){(bf16)p0, (bf16)p1};
        }
#pragma unroll
        for (int e = 0; e < 16; e += 2) {   // strip 1: t = 32..63
            float p0 = __builtin_amdgcn_exp2f(sc1[e]);
            float p1 = __builtin_amdgcn_exp2f(sc1[e + 1]);
            rs += p0 + p1;
            *(bf16x2*)&Pw[(4 + (e >> 2)) * 256 + l31 * 8 + (e & 3) + 4 * half] = (bf16x2){(bf16)p0, (bf16)p1};
        }
        l_i += rs;
        // PV: O^T[hd][q] += V^T-frag x P-frag
#pragma unroll
        for (int kb = 0; kb < 4; ++kb) {
            bf16x8 pf = *(const bf16x8*)&Pw[(2 * kb + half) * 256 + l31 * 8];
            bf16x8 v0 = *(const bf16x8*)&Vt[(2 * kb + half) * 512 + l31 * 8];
            bf16x8 v1 = *(const bf16x8*)&Vt[(2 * kb + half) * 512 + (32 + l31) * 8];
            o0 = mfma32(v0, pf, o0);
            o1 = mfma32(v1, pf, o1);
        }
        __syncthreads();
    }
    // combine the two SIMD-halves' partial l (disjoint t-subsets, same q)
    l_i += __shfl_xor(l_i, 32);
    // epilogue: transpose O^T->O via per-wave fp32 LDS slab (K/V/P LDS all dead past
    // the loop's final barrier), write unnormalized fp32 partial, coalesced.
    float* slab = (float*)SMEM + wave * 1184;   // 32 q x stride 36 floats
    const int s_base = q0blk + wave * 32;
#pragma unroll
    for (int s2 = 0; s2 < 2; ++s2) {
        const floatx16 oo = s2 ? o1 : o0;
#pragma unroll
        for (int e = 0; e < 16; ++e) {
            int hd = (e & 3) + 8 * (e >> 2) + 4 * half;
            slab[l31 * 36 + hd] = oo[e];
        }
#pragma unroll
        for (int p = 0; p < 2; ++p) {
            int q = p * 16 + (lane >> 2), part = lane & 3;
            float4 va = *(const float4*)&slab[q * 36 + part * 8];
            float4 vb = *(const float4*)&slab[q * 36 + part * 8 + 4];
            float* dst = Op + ((size_t)(tp * 32 + bh) * S_LEN + s_base + q) * HD_DIM + s2 * 32 + part * 8;
            *(float4*)dst = va;
            *(float4*)(dst + 4) = vb;
        }
    }
    if (half == 0) lp[tp * 65536 + bh * S_LEN + s_base + l31] = l_i;
}

// ---------------- combine: ctx[b,s,h*64+hd] = (O0+O1)/(l0+l1), cast bf16 ----------------
__global__ __launch_bounds__(256) void combine(const float* __restrict__ Op,
                                               const float* __restrict__ lp,
                                               bf16* __restrict__ ctx) {
    int idx = blockIdx.x * 256 + threadIdx.x;   // 1,048,576 threads, 4 hd each
    int sg = idx >> 4;                           // [0, 65536): bh*2048 + sl
    int hd = (idx & 15) * 4;
    float4 a = *(const float4*)&Op[(size_t)sg * 64 + hd];
    float4 b = *(const float4*)&Op[4194304 + (size_t)sg * 64 + hd];
    float inv = 1.f / (lp[sg] + lp[65536 + sg]);
    int bb = sg >> 15, h = (sg >> 11) & 15, sl = sg & 2047;
    bf16x4 o = { (bf16)((a.x + b.x) * inv), (bf16)((a.y + b.y) * inv),
                 (bf16)((a.z + b.z) * inv), (bf16)((a.w + b.w) * inv) };
    *(bf16x4*)&ctx[((size_t)(bb * S_LEN + sl)) * D_DIM + h * HD_DIM + hd] = o;
}

extern "C" void kernel_launch(void* const* d_in, const int* in_sizes, int n_in,
                              void* d_out, int out_size, void* d_ws, size_t ws_size,
                              hipStream_t stream) {
    const float* query = (const float*)d_in[0];
    const float* key   = (const float*)d_in[1];
    const float* value = (const float*)d_in[2];
    const float* Wq = (const float*)d_in[3];
    const float* bq = (const float*)d_in[4];
    const float* Wk = (const float*)d_in[5];
    const float* bk = (const float*)d_in[6];
    const float* Wv = (const float*)d_in[7];
    const float* bv = (const float*)d_in[8];
    const float* Wo = (const float*)d_in[9];
    const float* bo = (const float*)d_in[10];
    float* out = (float*)d_out;

    // workspace layout: attn-live buffers first, then one contiguous region of
    // attn-dead buffers that the fp32 partials (34 MB) alias. Total 36M elems = 72 MB.
    bf16* ws0 = (bf16*)d_ws;
    const size_t M1 = 1u << 20;
    bf16* WoT = ws0;                 // 1M  (live until out-proj)
    bf16* Qb  = WoT + M1;            // 4M  [b,h,s,hd]
    bf16* Kb  = Qb + 4 * M1;         // 4M
    bf16* Vtb = Kb + 4 * M1;         // 4M  [b,h,hd,s]
    bf16* SCR = Vtb + 4 * M1;        // 23M scratch (dead during attn)
    bf16* Qc  = SCR;                 // 4M
    bf16* Kc  = Qc + 4 * M1;         // 4M
    bf16* Vc  = Kc + 4 * M1;         // 4M
    bf16* WqT = Vc + 4 * M1;         // 1M
    bf16* WkT = WqT + M1;            // 1M
    bf16* WvT = WkT + M1;            // 1M
    bf16* Vb  = WvT + M1;            // 4M  [b,h,s,hd]
    bf16* ctx = Vb + 4 * M1;         // 4M  [b,s,D] (written by combine, after Op reads)
    float* Op = (float*)SCR;         // 2 x 65536 x 64 fp32 = 33.5 MB, aliases Qc..Vb
    float* lp = Op + 8388608;        // 2 x 65536 fp32 = 0.5 MB (ends well before ctx)

    dim3 blk(256);

    PrepArgs pa;
    pa.cast_src[0] = query; pa.cast_src[1] = key; pa.cast_src[2] = value;
    pa.cast_dst[0] = Qc;    pa.cast_dst[1] = Kc;  pa.cast_dst[2] = Vc;
    pa.w_src[0] = Wq; pa.w_src[1] = Wk; pa.w_src[2] = Wv;
    pa.w_dst[0] = WqT; pa.w_dst[1] = WkT; pa.w_dst[2] = WvT;
    pa.wo = Wo; pa.wo_t = WoT;
    prep<<<dim3(16384), blk, 0, stream>>>(pa);

    GemmArgs qkv;
    qkv.p[0] = {Qc, WqT, bq, Qb, nullptr, QSCALE};
    qkv.p[1] = {Kc, WkT, bk, Kb, nullptr, 1.0f};
    qkv.p[2] = {Vc, WvT, bv, Vb, nullptr, 1.0f};
    qkv.mode = 1;
    gemm_bt<<<dim3(32, 8, 3), blk, 0, stream>>>(qkv);

    transpose2d<<<dim3(64, 2, 32), blk, 0, stream>>>(Vb, Vtb, 2048, 64);

    attn<<<dim3(1024), blk, 0, stream>>>(Qb, Kb, Vtb, Op, lp);

    combine<<<dim3(4096), blk, 0, stream>>>(Op, lp, ctx);

    GemmArgs og;
    og.p[0] = {ctx, WoT, bo, nullptr, out, 1.0f};
    og.p[1] = og.p[0]; og.p[2] = og.p[0];
    og.mode = 0;
    gemm_bt<<<dim3(32, 8, 1), blk, 0, stream>>>(og);
}